// Round 1
// baseline (149.902 us; speedup 1.0000x reference)
//
#include <hip/hip_runtime.h>

// AliasFreeActivation fused kernel (MI355X / gfx950)
//
// Math (derived from the reference, verified index-by-index):
//   up (x4, 24 taps, pad 13/10+3):  hi[i]   = sum_m x[m] * up[10 + i - 4m]
//   down (x2, 12 taps, pad 5/5) + crop 10:  out[o] = sum_k hi[2o+15+k] * down[11-k]
//   => only hi[15..128] (114 samples/axis) needed; local l = i-15:
//      hi_l[l] = sum_{t=0..5} x[m0+t] * up[c0-4t],  m0 = (l+5)>>2,  c0 = 20+((l+1)&3)
//      input taps m stay in [1,34]  -> no boundary handling anywhere.
//   Pass order re-arranged (all linear): upH -> (upW + leaky + downW fused) -> downH.
//
// One (b,c) plane per 256-thread block. LDS: tH[114][35] + t2[114][53] = 40.1 KB
// -> 4 blocks/CU. All filter/array indices are compile-time constants
// (segment-relative), so xr/r/acc/rr stay in VGPRs.

__global__ __launch_bounds__(256, 4)
void afa_kernel(const float* __restrict__ x,
                const float* __restrict__ upf,
                const float* __restrict__ dnf,
                float* __restrict__ out)
{
    __shared__ float tH[114 * 35];   // [lh][mw-1], stride 35 (gcd(35,32)=1)
    __shared__ float t2[114 * 53];   // [lh][ow],   stride 53 (gcd(53,32)=1)

    const int plane = blockIdx.x;
    const int tid   = threadIdx.x;
    const float* __restrict__ xp = x + (size_t)plane * (36 * 36);
    float* __restrict__ op       = out + (size_t)plane * (52 * 52);

    // 24-tap up filter -> registers (uniform addresses -> scalar loads)
    float up[24];
#pragma unroll
    for (int i = 0; i < 24; ++i) up[i] = upf[i];

    // ---------------- Pass 1: upsample along H ----------------
    // thread (mw in [1,34], s in [0,6)) computes tH[20s + j][mw-1], j<jmax
    if (tid < 204) {
        const int s  = tid / 34;          // segment 0..5 (lh block of 20)
        const int mw = tid % 34 + 1;      // input column 1..34

        float xr[11];                      // x rows 5s+1 .. 5s+11 (clamped)
#pragma unroll
        for (int jj = 0; jj < 11; ++jj) {
            int row = 5 * s + 1 + jj;
            row = row > 35 ? 35 : row;     // clamp; clamped values never used
            xr[jj] = xp[row * 36 + mw];
        }
        const int lh0  = 20 * s;
        const int jmax = (s == 5) ? 14 : 20;   // lh < 114
#pragma unroll
        for (int j = 0; j < 20; ++j) {
            if (j < jmax) {
                const int rel = ((j + 5) >> 2) - 1;     // compile-time
                const int c0  = 20 + ((j + 1) & 3);     // compile-time
                float acc = 0.f;
#pragma unroll
                for (int t = 0; t < 6; ++t)
                    acc = fmaf(xr[rel + t], up[c0 - 4 * t], acc);
                tH[(lh0 + j) * 35 + (mw - 1)] = acc;
            }
        }
    }
    __syncthreads();

    // 12-tap down filter -> registers
    float dn[12];
#pragma unroll
    for (int i = 0; i < 12; ++i) dn[i] = dnf[i];

    // ---------- Pass 2: upsample along W + leaky_relu + downsample along W ----------
    // thread (lh in [0,114), p in {0,1}) computes t2[lh][26p .. 26p+25]
    if (tid < 228) {
        const int lh = tid % 114;
        const int p  = tid / 114;

        float r[21];                       // tH[lh][13p .. 13p+20]
#pragma unroll
        for (int jj = 0; jj < 21; ++jj)
            r[jj] = tH[lh * 35 + 13 * p + jj];

        float acc[26];
#pragma unroll
        for (int o = 0; o < 26; ++o) acc[o] = 0.f;

#pragma unroll
        for (int j = 0; j < 62; ++j) {     // lw = 52p + j
            const int rel = ((j + 5) >> 2) - 1;
            const int c0  = 20 + ((j + 1) & 3);
            float h = 0.f;
#pragma unroll
            for (int t = 0; t < 6; ++t)
                h = fmaf(r[rel + t], up[c0 - 4 * t], h);
            h = h < 0.f ? 0.2f * h : h;    // leaky_relu in high-res domain
#pragma unroll
            for (int k = 0; k < 12; ++k) { // scatter into down-W accumulators
                const int jk = j - k;
                if (jk >= 0 && (jk & 1) == 0 && (jk >> 1) < 26) {
                    acc[jk >> 1] = fmaf(h, dn[11 - k], acc[jk >> 1]);
                }
            }
        }
#pragma unroll
        for (int o = 0; o < 26; ++o)
            t2[lh * 53 + 26 * p + o] = acc[o];
    }
    __syncthreads();

    // ---------------- Pass 3: downsample along H + store ----------------
    // thread (ow in [0,52), s in [0,4)) computes out[13s + j][ow], j in [0,13)
    if (tid < 208) {
        const int ow = tid % 52;
        const int s  = tid / 52;

        float rr[36];                      // t2 rows 26s .. 26s+35 at column ow
#pragma unroll
        for (int jj = 0; jj < 36; ++jj)
            rr[jj] = t2[(26 * s + jj) * 53 + ow];

#pragma unroll
        for (int j = 0; j < 13; ++j) {
            float acc = 0.f;
#pragma unroll
            for (int k = 0; k < 12; ++k)
                acc = fmaf(rr[2 * j + k], dn[11 - k], acc);
            op[(13 * s + j) * 52 + ow] = acc;
        }
    }
}

extern "C" void kernel_launch(void* const* d_in, const int* in_sizes, int n_in,
                              void* d_out, int out_size, void* d_ws, size_t ws_size,
                              hipStream_t stream)
{
    const float* x  = (const float*)d_in[0];   // (16,512,36,36)
    const float* up = (const float*)d_in[1];   // (24,)
    const float* dn = (const float*)d_in[2];   // (12,)
    float* out = (float*)d_out;                // (16,512,52,52)

    const int planes = 16 * 512;               // 8192 blocks, one plane each
    afa_kernel<<<dim3(planes), dim3(256), 0, stream>>>(x, up, dn, out);
}

// Round 2
// 145.694 us; speedup vs baseline: 1.0289x; 1.0289x over previous
//
#include <hip/hip_runtime.h>

// AliasFreeActivation fused kernel, v2: plane-PAIR per block as float2.
//
// Math (verified, identical to v1 which passed):
//   up (x4, 24 taps):  hi[l] = sum_{t=0..5} x[m0+t] * up[c0-4t],
//       m0 = (l+5)>>2, c0 = 20+((l+1)&3), l in [0,114), taps stay in [1,34].
//   down (x2, 12 taps) + crop 10: out[o] = sum_k hl[2o+k] * dn[11-k].
//   Pass order: upH -> (upW + leaky + downW fused) -> downH.
//
// v2 changes:
//  - 2 planes per block (q0=2*bid, q1=q0+1) processed as float2 lanes ->
//    all addressing / LDS instrs / control flow amortized 2x; FMAs become
//    v_pk_fma_f32 via __builtin_elementwise_fma on ext_vector_type(2).
//  - LDS overlay: pass2 threads read ONLY their own tH row into registers;
//    an extra __syncthreads() after those reads makes it safe to write t2
//    into the SAME buffer. LDS = 114*53*8 = 48336 B -> 3 blocks/CU.

typedef float v2f __attribute__((ext_vector_type(2)));

static __device__ __forceinline__ v2f vsplat(float s) { v2f v; v.x = s; v.y = s; return v; }

__global__ __launch_bounds__(256, 3)
void afa_kernel(const float* __restrict__ x,
                const float* __restrict__ upf,
                const float* __restrict__ dnf,
                float* __restrict__ out)
{
    // Overlaid buffer: tH rows at stride 35 (first 3990 elems), t2 rows at stride 53.
    __shared__ v2f buf[114 * 53];   // 48336 bytes

    const int tid = threadIdx.x;
    const size_t q0 = (size_t)blockIdx.x * 2;
    const float* __restrict__ xp0 = x + q0 * (36 * 36);
    const float* __restrict__ xp1 = xp0 + (36 * 36);
    float* __restrict__ op0 = out + q0 * (52 * 52);
    float* __restrict__ op1 = op0 + (52 * 52);

    // filters -> uniform (scalar) registers
    float up[24];
#pragma unroll
    for (int i = 0; i < 24; ++i) up[i] = upf[i];
    float dn[12];
#pragma unroll
    for (int i = 0; i < 12; ++i) dn[i] = dnf[i];

    // ---------------- Pass 1: upsample along H ----------------
    // thread (s in [0,6), mw in [1,34]) -> tH[20s+j][mw-1], j<jmax
    if (tid < 204) {
        const int s  = tid / 34;
        const int mw = tid % 34 + 1;

        v2f xr[11];                       // x rows 5s+1 .. 5s+11 (clamped), both planes
#pragma unroll
        for (int jj = 0; jj < 11; ++jj) {
            int row = 5 * s + 1 + jj;
            row = row > 35 ? 35 : row;    // clamp; clamped values never used
            xr[jj].x = xp0[row * 36 + mw];
            xr[jj].y = xp1[row * 36 + mw];
        }
        const int lh0  = 20 * s;
        const int jmax = (s == 5) ? 14 : 20;  // lh < 114
#pragma unroll
        for (int j = 0; j < 20; ++j) {
            if (j < jmax) {
                const int rel = ((j + 5) >> 2) - 1;   // compile-time
                const int c0  = 20 + ((j + 1) & 3);   // compile-time
                v2f acc = vsplat(0.f);
#pragma unroll
                for (int t = 0; t < 6; ++t)
                    acc = __builtin_elementwise_fma(xr[rel + t], vsplat(up[c0 - 4 * t]), acc);
                buf[(lh0 + j) * 35 + (mw - 1)] = acc;  // tH region
            }
        }
    }
    __syncthreads();

    // ---------- Pass 2: upW + leaky + downW, reading own tH row into regs ----------
    const int lh = tid % 114;
    const int p  = tid / 114;   // valid for tid<228
    v2f r[21];
    if (tid < 228) {
#pragma unroll
        for (int jj = 0; jj < 21; ++jj)
            r[jj] = buf[lh * 35 + 13 * p + jj];       // consecutive -> ds_read2_b64
    }
    __syncthreads();   // ALL tH reads complete before any t2 write (buffer overlay)

    if (tid < 228) {
        v2f acc[26];
#pragma unroll
        for (int o = 0; o < 26; ++o) acc[o] = vsplat(0.f);

#pragma unroll
        for (int j = 0; j < 62; ++j) {                 // lw = 52p + j
            const int rel = ((j + 5) >> 2) - 1;
            const int c0  = 20 + ((j + 1) & 3);
            v2f h = vsplat(0.f);
#pragma unroll
            for (int t = 0; t < 6; ++t)
                h = __builtin_elementwise_fma(r[rel + t], vsplat(up[c0 - 4 * t]), h);
            // leaky_relu(h) = max(h,0) + 0.2*min(h,0)
            v2f hneg = __builtin_elementwise_min(h, vsplat(0.f));
            v2f hpos = __builtin_elementwise_max(h, vsplat(0.f));
            h = __builtin_elementwise_fma(hneg, vsplat(0.2f), hpos);
#pragma unroll
            for (int k = 0; k < 12; ++k) {             // scatter into down-W accs
                const int jk = j - k;
                if (jk >= 0 && (jk & 1) == 0 && (jk >> 1) < 26)
                    acc[jk >> 1] = __builtin_elementwise_fma(h, vsplat(dn[11 - k]), acc[jk >> 1]);
            }
        }
#pragma unroll
        for (int o = 0; o < 26; ++o)
            buf[lh * 53 + 26 * p + o] = acc[o];        // t2 region (overlay, post-sync)
    }
    __syncthreads();

    // ---------------- Pass 3: downsample along H + store ----------------
    if (tid < 208) {
        const int ow = tid % 52;
        const int s  = tid / 52;

        v2f rr[36];                                    // t2 rows 26s..26s+35 at col ow
#pragma unroll
        for (int jj = 0; jj < 36; ++jj)
            rr[jj] = buf[(26 * s + jj) * 53 + ow];

#pragma unroll
        for (int j = 0; j < 13; ++j) {
            v2f acc = vsplat(0.f);
#pragma unroll
            for (int k = 0; k < 12; ++k)
                acc = __builtin_elementwise_fma(rr[2 * j + k], vsplat(dn[11 - k]), acc);
            const int o = (13 * s + j) * 52 + ow;
            op0[o] = acc.x;
            op1[o] = acc.y;
        }
    }
}

extern "C" void kernel_launch(void* const* d_in, const int* in_sizes, int n_in,
                              void* d_out, int out_size, void* d_ws, size_t ws_size,
                              hipStream_t stream)
{
    const float* x  = (const float*)d_in[0];   // (16,512,36,36)
    const float* up = (const float*)d_in[1];   // (24,)
    const float* dn = (const float*)d_in[2];   // (12,)
    float* out = (float*)d_out;                // (16,512,52,52)

    const int pairs = 16 * 512 / 2;            // 4096 blocks, one plane-pair each
    afa_kernel<<<dim3(pairs), dim3(256), 0, stream>>>(x, up, dn, out);
}